// Round 11
// baseline (341.625 us; speedup 1.0000x reference)
//
#include <hip/hip_runtime.h>
#include <hip/hip_bf16.h>
#include <cmath>

// ---------------------------------------------------------------------------
// TransformerEncoderLayer, fp32 in/out (bf16 MFMA internally), MI355X gfx950.
// Pipeline: prep(qkv-transpose + LN1) -> QKVT(qkv GEMM ∥ proj/fc1/fc2
//           transposes, ONE launch) -> flash-attn(pipelined)
//           -> GEMM(proj,+x -> f32 x2) -> LN2 -> GEMM(fc1,GELU)
//           -> GEMM(fc2,+x2 -> f32 out)
// v13 = R10 (proven 334.3us) + transpose/GEMM co-scheduling:
//   proj/fc1/fc2 weight transposes (9216 tiles, ~57MB traffic) are not
//   needed until later kernels but serialized in prep. qkv GEMM runs at 16%
//   HBM -> merge the transposes into the qkv launch as a blockIdx branch
//   (GEMM = blocks 0..767, transposes = 768..9983). Transpose scratch
//   aliases the GEMM's Alds (LDS stays 64KB, 2 blk/CU). GEMM blocks
//   dispatch first; transposes backfill spare CUs/bandwidth.
// Evidence ledger (R1-R10), families CLOSED:
//   - GEMM BN=128 (fc1): 2-buffer __syncthreads loop; fc1/fc2 both plateau
//     at ~590 TF; bigger tiles / 8-phase / deep prefetch / 64x64-wave all
//     REGRESSED (R2/R3/R4/R8). fc2 geometry can't feed the m201 256² escape.
//   - GEMM BN=64 (proj/fc2): NBUF=3 + vmcnt(6) counted prefetch (R6).
//   - attn (R10): KVBLK=64 double-buffered stage-before-compute, 3 blk/CU;
//     Q prescaled 0.125*log2e -> bare exp2; row-sum via ones-MFMA.
// ---------------------------------------------------------------------------

typedef __hip_bfloat16 bf16;
typedef __bf16 bf16x8 __attribute__((ext_vector_type(8)));
typedef __bf16 bf16x4v __attribute__((ext_vector_type(4)));
typedef float  f32x4  __attribute__((ext_vector_type(4)));

#define CB 2
#define CN 2048
#define CE 1024
#define CH 16
#define CD 64
#define CMLP 4096
#define CM (CB*CN)   // 4096 tokens

#define PS2 72       // attn P-tile LDS row stride (elems), 64 keys + pad

#define QPRE 0.18033688011112042f   // 0.125 * log2(e), folded into Q
#if __has_builtin(__builtin_amdgcn_exp2f)
#define EXP2(s) __builtin_amdgcn_exp2f(s)
#else
#define EXP2(s) __expf((s)*0.69314718055994531f)
#endif

__device__ __forceinline__ float b2f(bf16 v){ return __bfloat162float(v); }
__device__ __forceinline__ bf16  f2b(float v){ return __float2bfloat16(v); }

__device__ __forceinline__ void gl_lds16(const void* g, void* l){
  __builtin_amdgcn_global_load_lds((__attribute__((address_space(1))) void*)g,
                                   (__attribute__((address_space(3))) void*)l,
                                   16, 0, 0);
}

#define FENCE asm volatile("" ::: "memory")
#define BAR   do{ FENCE; __builtin_amdgcn_s_barrier(); FENCE; }while(0)
#define VMW6  asm volatile("s_waitcnt vmcnt(6)" ::: "memory")
#define VMW0  asm volatile("s_waitcnt vmcnt(0)" ::: "memory")

// prep: qkv weight transpose (f32 [1024,3072] -> bf16 [3072,1024]) + LN1.
// blocks 0..3071: qkv transpose tiles; blocks 3072..7167: LN1 rows.
__global__ __launch_bounds__(256) void prep_k(
  const float* __restrict__ i0, bf16* __restrict__ o0,
  const float* __restrict__ x,  const float* __restrict__ g,
  const float* __restrict__ be, bf16* __restrict__ lnout)
{
  __shared__ float tile[32][33];
  __shared__ float red[8];
  __shared__ float mu_s, rs_s;
  int t = blockIdx.x;
  const int tid = threadIdx.x;
  if(t >= 3072){
    // ---- LayerNorm row ----
    const int row = t - 3072;
    const float4 v4 = ((const float4*)(x + (size_t)row*CE))[tid];
    float v[4] = {v4.x, v4.y, v4.z, v4.w};
    float s=0.f, s2=0.f;
    #pragma unroll
    for(int i=0;i<4;i++){ s+=v[i]; s2+=v[i]*v[i]; }
    #pragma unroll
    for(int off=32; off>0; off>>=1){ s += __shfl_down(s,off); s2 += __shfl_down(s2,off); }
    const int wv=tid>>6, ln=tid&63;
    if(ln==0){ red[wv]=s; red[4+wv]=s2; }
    __syncthreads();
    if(tid==0){
      float S=red[0]+red[1]+red[2]+red[3], S2=red[4]+red[5]+red[6]+red[7];
      float mu=S/CE;
      mu_s=mu; rs_s=rsqrtf(S2/CE - mu*mu + 1e-5f);
    }
    __syncthreads();
    const float mu=mu_s, rs=rs_s;
    #pragma unroll
    for(int i=0;i<4;i++){
      int c=tid*4+i;
      lnout[(size_t)row*CE+c] = f2b((v[i]-mu)*rs*g[c] + be[c]);
    }
    return;
  }
  // ---- qkv transpose tile: K=1024, N=3072, nx=96 ----
  const int n0 = (t%96)*32, k0 = (t/96)*32;
  const int tx = tid & 31;
  const int ty = tid >> 5;   // 0..7
  #pragma unroll
  for(int i=0;i<32;i+=8) tile[ty+i][tx] = i0[(size_t)(k0+ty+i)*3072 + n0+tx];
  __syncthreads();
  #pragma unroll
  for(int i=0;i<32;i+=8) o0[(size_t)(n0+ty+i)*1024 + k0+tx] = f2b(tile[tx][ty+i]);
}

// LayerNorm: one row (E=1024) per 256-thread block; f32 in -> bf16 out
__global__ __launch_bounds__(256) void ln_k(const float* __restrict__ x,
                                            const float* __restrict__ g,
                                            const float* __restrict__ be,
                                            bf16* __restrict__ out){
  const int row = blockIdx.x;
  const int t = threadIdx.x;
  const float4 v4 = ((const float4*)(x + (size_t)row*CE))[t];
  float v[4] = {v4.x, v4.y, v4.z, v4.w};
  float s=0.f, s2=0.f;
  #pragma unroll
  for(int i=0;i<4;i++){ s+=v[i]; s2+=v[i]*v[i]; }
  #pragma unroll
  for(int off=32; off>0; off>>=1){ s += __shfl_down(s,off); s2 += __shfl_down(s2,off); }
  __shared__ float red[8];
  __shared__ float mu_s, rs_s;
  const int wv=t>>6, ln=t&63;
  if(ln==0){ red[wv]=s; red[4+wv]=s2; }
  __syncthreads();
  if(t==0){
    float S=red[0]+red[1]+red[2]+red[3], S2=red[4]+red[5]+red[6]+red[7];
    float mu=S/CE;
    mu_s=mu; rs_s=rsqrtf(S2/CE - mu*mu + 1e-5f);
  }
  __syncthreads();
  const float mu=mu_s, rs=rs_s;
  #pragma unroll
  for(int i=0;i<4;i++){
    int c=t*4+i;
    out[(size_t)row*CE+c] = f2b((v[i]-mu)*rs*g[c] + be[c]);
  }
}

#define EP_QKV 0
#define EP_RES 1
#define EP_GELU 2

// qkvt_k: qkv GEMM (blocks 0..767) ∥ proj/fc1/fc2 weight transposes
// (blocks 768..9983). GEMM body identical to gemm_k<EP_QKV,128>;
// transpose branch aliases its scratch onto Alds (LDS stays 64KB).
__global__ __launch_bounds__(256,2) void qkvt_k(
  const bf16* __restrict__ A, const bf16* __restrict__ BT,
  const float* __restrict__ bias,
  bf16* __restrict__ Cq, bf16* __restrict__ Ck, bf16* __restrict__ Cv,
  const float* __restrict__ i1, bf16* __restrict__ o1,
  const float* __restrict__ i2, bf16* __restrict__ o2,
  const float* __restrict__ i3, bf16* __restrict__ o3)
{
  __shared__ __align__(16) bf16 Alds[2][128*64];
  __shared__ __align__(16) bf16 Blds[2][128*64];
  const int tid = threadIdx.x;

  if(blockIdx.x >= 768){
    // ---- transpose branch: f32 [K,N] -> bf16 [N,K] ----
    float (*tile)[33] = (float(*)[33])(&Alds[0][0]);   // 4.2KB alias
    int t = blockIdx.x - 768;
    const float* in; bf16* out; int K, N, nx;
    if(t < 1024){            in=i1; out=o1; K=1024; N=1024; nx=32; }
    else if(t < 5120){ t-=1024; in=i2; out=o2; K=1024; N=4096; nx=128; }
    else {             t-=5120; in=i3; out=o3; K=4096; N=1024; nx=32; }
    const int n0 = (t%nx)*32, k0 = (t/nx)*32;
    const int tx = tid & 31;
    const int ty = tid >> 5;   // 0..7
    #pragma unroll
    for(int i=0;i<32;i+=8) tile[ty+i][tx] = in[(size_t)(k0+ty+i)*N + n0+tx];
    __syncthreads();
    #pragma unroll
    for(int i=0;i<32;i+=8) out[(size_t)(n0+ty+i)*K + k0+tx] = f2b(tile[tx][ty+i]);
    return;
  }

  // ---- qkv GEMM: A[4096,1024] * BT[3072,1024]^T, scatter epilogue ----
  constexpr int BN = 128;
  constexpr int NJ = 4;
  const int Ksz = 1024;
  const int wave = tid>>6, lane = tid&63;
  const int m16 = lane&15, quad = lane>>4;
  const int wi = wave>>1, wj = wave&1;

  const int lin = blockIdx.x;          // 0..767, same remap domain as before
  const int m_idx = (lin&7) + 8*((lin>>3)&3);
  const int n_idx = lin>>5;
  const size_t m0 = (size_t)m_idx*128;
  const size_t n0 = (size_t)n_idx*BN;

  f32x4 acc[4][NJ] = {};

  const int srow8 = lane>>3;
  const int schk  = ((lane&7)^srow8)*8;
  const bf16* pA = A  + (m0 + 32*wave      + srow8)*(size_t)Ksz + schk;
  const bf16* pB = BT + (n0 + (BN/4)*wave  + srow8)*(size_t)Ksz + schk;

  auto stage = [&](int buf, const bf16* gA, const bf16* gB){
    bf16* lA = &Alds[buf][wave*2048];
    bf16* lB = &Blds[buf][wave*(BN*16)];
    #pragma unroll
    for(int j=0;j<4;j++)  gl_lds16(gA + (size_t)(j*8)*Ksz, lA + j*512);
    #pragma unroll
    for(int j=0;j<NJ;j++) gl_lds16(gB + (size_t)(j*8)*Ksz, lB + j*512);
  };
  auto compute = [&](int buf){
    #pragma unroll
    for(int w=0;w<2;w++){
      const int sw = (m16&7);
      bf16x8 af[4], bfr[NJ];
      #pragma unroll
      for(int i=0;i<4;i++){
        const int row = wi*64+16*i+m16;
        af[i] = *(const bf16x8*)(&Alds[buf][row*64 + ((w*4+quad)^sw)*8]);
      }
      #pragma unroll
      for(int j=0;j<NJ;j++){
        const int row = wj*(BN/2)+16*j+m16;
        bfr[j] = *(const bf16x8*)(&Blds[buf][row*64 + ((w*4+quad)^sw)*8]);
      }
      #pragma unroll
      for(int i=0;i<4;i++)
        #pragma unroll
        for(int j=0;j<NJ;j++)
          acc[i][j] = __builtin_amdgcn_mfma_f32_16x16x32_bf16(af[i], bfr[j], acc[i][j], 0,0,0);
    }
  };

  const int kIters = Ksz/64;
  stage(0, pA, pB); pA += 64; pB += 64;
  for(int kb=0; kb<kIters; ++kb){
    __syncthreads();                  // tile kb landed; compute(kb-1) done
    if(kb+1<kIters){ stage((kb+1)&1, pA, pB); pA += 64; pB += 64; }
    compute(kb&1);                    // overlaps tile kb+1 load latency
  }

  // scatter epilogue (Q prescaled by QPRE)
  #pragma unroll
  for(int i=0;i<4;i++){
    #pragma unroll
    for(int j=0;j<NJ;j++){
      const int col = (int)n0 + wj*(BN/2) + 16*j + m16;
      const float bcol = bias[col];
      #pragma unroll
      for(int r=0;r<4;r++){
        const int row = (int)m0 + wi*64 + 16*i + quad*4 + r;
        float v = acc[i][j][r] + bcol;
        const int b = row>>11, n = row&2047;
        const int which = col>>10, cc = col&1023;
        const int h = cc>>6, d = cc&63;
        if(which==0)      Cq[(((size_t)(b*CH+h))*CN+n)*CD + d] = f2b(v*QPRE);
        else if(which==1) Ck[(((size_t)(b*CH+h))*CN+n)*CD + d] = f2b(v);
        else              Cv[(((size_t)(b*CH+h))*CD+d)*CN + n] = f2b(v);
      }
    }
  }
}

// C = A[M,K](bf16) * BT[N,K](bf16)^T (+f32 bias; epilogue per MODE)
// Tile 128 x BN, BK=64; 4 waves, each 64 x BN/2 (MI=4, NJ=BN/32).
// Requires gridDim.y == 32 (M=4096) for the XCD remap.
template<int MODE, int BN>
__global__ __launch_bounds__(256,2) void gemm_k(
  const bf16* __restrict__ A, const bf16* __restrict__ BT,
  const float* __restrict__ bias, const float* __restrict__ res,
  float* __restrict__ Cf, bf16* __restrict__ Cb,
  int Ksz, int Nsz)
{
  constexpr int NJ = BN/32;           // B frags per wave (2 or 4)
  constexpr int NBUF = (BN==64) ? 3 : 2;
  __shared__ __align__(16) bf16 Alds[NBUF][128*64];
  __shared__ __align__(16) bf16 Blds[NBUF][BN*64];
  const int tid = threadIdx.x;
  const int wave = tid>>6, lane = tid&63;
  const int m16 = lane&15, quad = lane>>4;
  const int wi = wave>>1, wj = wave&1;

  // XCD co-location: same m-tile -> same lin%8 -> same XCD L2 holds A-tile.
  const int lin = blockIdx.x + gridDim.x*blockIdx.y;
  const int m_idx = (lin&7) + 8*((lin>>3)&3);
  const int n_idx = lin>>5;
  const size_t m0 = (size_t)m_idx*128;
  const size_t n0 = (size_t)n_idx*BN;

  f32x4 acc[4][NJ] = {};

  // staging: instr j covers 8 rows; lane -> row +lane/8, swizzled chunk
  const int srow8 = lane>>3;                   // 0..7
  const int schk  = ((lane&7)^srow8)*8;        // elem offset, XOR swizzle
  const bf16* pA = A  + (m0 + 32*wave      + srow8)*(size_t)Ksz + schk;
  const bf16* pB = BT + (n0 + (BN/4)*wave  + srow8)*(size_t)Ksz + schk;

  auto stage = [&](int buf, const bf16* gA, const bf16* gB){
    bf16* lA = &Alds[buf][wave*2048];          // 32 rows * 64 elems
    bf16* lB = &Blds[buf][wave*(BN*16)];       // BN/4 rows * 64 elems
    #pragma unroll
    for(int j=0;j<4;j++)  gl_lds16(gA + (size_t)(j*8)*Ksz, lA + j*512);
    #pragma unroll
    for(int j=0;j<NJ;j++) gl_lds16(gB + (size_t)(j*8)*Ksz, lB + j*512);
  };
  auto compute = [&](int buf){
    #pragma unroll
    for(int w=0;w<2;w++){
      const int sw = (m16&7);
      bf16x8 af[4], bfr[NJ];
      #pragma unroll
      for(int i=0;i<4;i++){
        const int row = wi*64+16*i+m16;
        af[i] = *(const bf16x8*)(&Alds[buf][row*64 + ((w*4+quad)^sw)*8]);
      }
      #pragma unroll
      for(int j=0;j<NJ;j++){
        const int row = wj*(BN/2)+16*j+m16;
        bfr[j] = *(const bf16x8*)(&Blds[buf][row*64 + ((w*4+quad)^sw)*8]);
      }
      #pragma unroll
      for(int i=0;i<4;i++)
        #pragma unroll
        for(int j=0;j<NJ;j++)
          acc[i][j] = __builtin_amdgcn_mfma_f32_16x16x32_bf16(af[i], bfr[j], acc[i][j], 0,0,0);
    }
  };

  const int kIters = Ksz/64;
  if constexpr (BN==64){
    // 3-buffer, 2-tile-ahead prefetch; counted vmcnt + raw barrier per iter.
    stage(0, pA, pB); pA += 64; pB += 64;
    stage(1, pA, pB); pA += 64; pB += 64;
    int bc = 0, bs = 2;
    for(int kb=0; kb<kIters; ++kb){
      if(kb==kIters-1){ VMW0; } else { VMW6; }   // own tile-kb loads landed
      BAR;                                        // -> all waves' tile kb
      if(kb+2<kIters){ stage(bs, pA, pB); pA += 64; pB += 64; }
      compute(bc);
      bc = (bc==2)?0:bc+1;
      bs = (bs==2)?0:bs+1;
    }
  } else {
    // Proven 2-buffer loop: ONE __syncthreads per iter (implicit vmcnt(0)
    // drain waits tile kb issued a full compute phase earlier).
    stage(0, pA, pB); pA += 64; pB += 64;
    for(int kb=0; kb<kIters; ++kb){
      __syncthreads();                  // tile kb landed; compute(kb-1) done
      if(kb+1<kIters){ stage((kb+1)&1, pA, pB); pA += 64; pB += 64; }
      compute(kb&1);                    // overlaps tile kb+1 load latency
    }
  }

  // epilogue: elem (row = m0+wi*64+16i+quad*4+r, col = n0+wj*(BN/2)+16j+m16)
  #pragma unroll
  for(int i=0;i<4;i++){
    #pragma unroll
    for(int j=0;j<NJ;j++){
      const int col = (int)n0 + wj*(BN/2) + 16*j + m16;
      const float bcol = bias[col];
      #pragma unroll
      for(int r=0;r<4;r++){
        const int row = (int)m0 + wi*64 + 16*i + quad*4 + r;
        float v = acc[i][j][r] + bcol;
        if constexpr (MODE==EP_RES){
          v += res[(size_t)row*Nsz+col];
          Cf[(size_t)row*Nsz+col] = v;
        } else { // EP_GELU: tanh-form, branch-free.
          const float u2 = 1.5957691216f*(v + 0.044715f*v*v*v);
          v = v * (1.f/(1.f + __expf(-u2)));
          Cb[(size_t)row*Nsz+col] = f2b(v);
        }
      }
    }
  }
}

// Flash attention v5 (pipelined): grid (16,32), XCD remap (all 16 q-blocks
// of one (b,h) share lin%8). 4 waves; wave = 32 q-rows. KVBLK=64, K/V
// double-buffered: stage(t+1) issued BEFORE compute(t), ONE barrier/iter.
// P-tile wave-private (no barrier). LDS ~50KB -> 3 blk/CU.
// Q pre-scaled -> bare exp2; row-sum via ones-MFMA.
// Q,K: bf16 [B,H,N,D]; Vt: bf16 [B,H,D,N]; O: bf16 [B,N,E] (col = h*64+d)
__global__ __launch_bounds__(256,2) void attn_k(
  const bf16* __restrict__ Q, const bf16* __restrict__ Kx,
  const bf16* __restrict__ Vt, bf16* __restrict__ O)
{
  const int lin = blockIdx.x + gridDim.x*blockIdx.y;
  const int bh = (lin&7) + 8*(lin>>7);
  const int qblk = (lin>>3)&15;
  const int b = bh>>4, h = bh&15;
  const int tid = threadIdx.x;
  const int wave = tid>>6, lane = tid&63;
  const int m16 = lane&15, quad = lane>>4;
  const int sw = m16&7;
  const int q0 = qblk*128 + wave*32;

  const bf16* Qb = Q  + (size_t)bh*CN*CD;
  const bf16* Kb = Kx + (size_t)bh*CN*CD;
  const bf16* Vb = Vt + (size_t)bh*CD*CN;

  bf16x8 qf[2][2];
  #pragma unroll
  for(int g=0;g<2;g++){
    const bf16* qp = Qb + (size_t)(q0+g*16+m16)*CD + quad*8;
    qf[g][0] = *(const bf16x8*)(qp);
    qf[g][1] = *(const bf16x8*)(qp + 32);
  }

  bf16x8 onesv;
  #pragma unroll
  for(int i=0;i<8;i++) onesv[i] = (__bf16)1.0f;

  f32x4 lacc[2] = {};
  f32x4 oacc[2][4] = {};

  __shared__ __align__(16) bf16 Klds[2][64*64];   // 8 KB per buf
  __shared__ __align__(16) bf16 Vlds[2][64*64];   // 8 KB per buf
  __shared__ __align__(16) bf16 Plds[4][32*PS2];  // 18 KB
  bf16* Pw = &Plds[wave][0];

  const int srow8 = lane>>3;                    // 0..7 (row in 8-group)
  const int kchk  = (lane&7) ^ srow8;           // swizzled chunk
  const bf16* pK = Kb + (size_t)(wave*16 + srow8)*CD + kchk*8;
  const bf16* pV = Vb + (size_t)(wave*16 + srow8)*CN + kchk*8;
  const int ldso = wave*1024;                   // 16 rows * 64 elems

  auto stage = [&](int buf, int kt){
    #pragma unroll
    for(int j=0;j<2;j++){
      gl_lds16(pK + ((size_t)kt + (size_t)j*8)*CD, &Klds[buf][ldso + j*512]);
      gl_lds16(pV + (size_t)j*8*CN + kt,           &Vlds[buf][ldso + j*512]);
    }
  };

  stage(0, 0);
  const int nT = CN/64;   // 32 tiles
  for(int t=0; t<nT; ++t){
    __syncthreads();                 // tile t landed; compute(t-1) done
    if(t+1<nT) stage((t+1)&1, (t+1)*64);
    const bf16* Kl = &Klds[t&1][0];
    const bf16* Vl = &Vlds[t&1][0];

    // S^T = K * Q^T : 4 f-tiles of 16 key-rows
    f32x4 sf0[4], sf1[4];
    #pragma unroll
    for(int f=0;f<4;f++){
      const bf16* kb = Kl + (f*16+m16)*64;
      bf16x8 k0 = *(const bf16x8*)(kb + ((quad   ^ sw)*8));
      bf16x8 k1 = *(const bf16x8*)(kb + (((quad+4)^ sw)*8));
      f32x4 t0 = {}, t1 = {};
      t0 = __builtin_amdgcn_mfma_f32_16x16x32_bf16(k0, qf[0][0], t0, 0,0,0);
      t0 = __builtin_amdgcn_mfma_f32_16x16x32_bf16(k1, qf[0][1], t0, 0,0,0);
      t1 = __builtin_amdgcn_mfma_f32_16x16x32_bf16(k0, qf[1][0], t1, 0,0,0);
      t1 = __builtin_amdgcn_mfma_f32_16x16x32_bf16(k1, qf[1][1], t1, 0,0,0);
      sf0[f]=t0; sf1[f]=t1;
    }
    // P = exp2(S) -> bf16, packed b64 stores into wave-private P-tile
    #pragma unroll
    for(int f=0;f<4;f++){
      bf16x4v p0, p1;
      #pragma unroll
      for(int r=0;r<4;r++){
        p0[r] = (__bf16)EXP2(sf0[f][r]);
        p1[r] = (__bf16)EXP2(sf1[f][r]);
      }
      *(bf16x4v*)(Pw + (size_t)m16*PS2      + f*16 + quad*4) = p0;
      *(bf16x4v*)(Pw + (size_t)(16+m16)*PS2 + f*16 + quad*4) = p1;
    }
    asm volatile("s_waitcnt lgkmcnt(0)" ::: "memory");
    // O += P * V ; li += P * 1  (2 c-chunks of 32 keys)
    #pragma unroll
    for(int c=0;c<2;c++){
      const bf16x8 ap0 = *(const bf16x8*)(Pw + (size_t)m16*PS2      + c*32 + quad*8);
      const bf16x8 ap1 = *(const bf16x8*)(Pw + (size_t)(16+m16)*PS2 + c*32 + quad*8);
      lacc[0] = __builtin_amdgcn_mfma_f32_16x16x32_bf16(ap0, onesv, lacc[0], 0,0,0);
      lacc[1] = __builtin_amdgcn_mfma_f32_16x16x32_bf16(ap1, onesv, lacc[1], 0,0,0);
      #pragma unroll
      for(int dt=0;dt<4;dt++){
        const int d = dt*16+m16;
        bf16x8 bv = *(const bf16x8*)(Vl + d*64 + (((c*4+quad) ^ sw)*8));
        oacc[0][dt] = __builtin_amdgcn_mfma_f32_16x16x32_bf16(ap0, bv, oacc[0][dt], 0,0,0);
        oacc[1][dt] = __builtin_amdgcn_mfma_f32_16x16x32_bf16(ap1, bv, oacc[1][dt], 0,0,0);
      }
    }
  }
  // lacc[g][r] = row-sum for q-row g*16+quad*4+r (same value in all 16 cols)
  #pragma unroll
  for(int g=0;g<2;g++){
    float linv[4];
    #pragma unroll
    for(int r=0;r<4;r++) linv[r] = 1.f / lacc[g][r];
    #pragma unroll
    for(int dt=0;dt<4;dt++){
      #pragma unroll
      for(int r=0;r<4;r++){
        const int row = q0 + g*16 + quad*4 + r;
        O[((size_t)(b*CN+row))*CE + h*CD + dt*16 + m16] = f2b(oacc[g][dt][r]*linv[r]);
      }
    }
  }
}

extern "C" void kernel_launch(void* const* d_in, const int* in_sizes, int n_in,
                              void* d_out, int out_size, void* d_ws, size_t ws_size,
                              hipStream_t stream)
{
  (void)in_sizes; (void)n_in; (void)out_size; (void)ws_size;
  const float* x     = (const float*)d_in[0];
  const float* w_qkv = (const float*)d_in[1];
  const float* b_qkv = (const float*)d_in[2];
  const float* w_proj= (const float*)d_in[3];
  const float* b_proj= (const float*)d_in[4];
  const float* g1    = (const float*)d_in[5];
  const float* be1   = (const float*)d_in[6];
  const float* g2    = (const float*)d_in[7];
  const float* be2   = (const float*)d_in[8];
  const float* w_fc1 = (const float*)d_in[9];
  const float* b_fc1 = (const float*)d_in[10];
  const float* w_fc2 = (const float*)d_in[11];
  const float* b_fc2 = (const float*)d_in[12];
  float* out = (float*)d_out;

  char* ws = (char*)d_ws;
  size_t off = 0;
  auto alloc = [&](size_t bytes)->char*{
    char* p = ws + off;
    off += (bytes + 255) & ~(size_t)255;
    return p;
  };
  bf16* wqkvT = (bf16*)alloc((size_t)3072*1024*2);  // [3E, E]
  bf16* wprojT= (bf16*)alloc((size_t)1024*1024*2);  // [E, E]
  bf16* wfc1T = (bf16*)alloc((size_t)4096*1024*2);  // [MLP, E]
  bf16* wfc2T = (bf16*)alloc((size_t)1024*4096*2);  // [E, MLP]
  bf16* h1    = (bf16*)alloc((size_t)CM*CE*2);      // LN out (reused for LN2)
  bf16* q     = (bf16*)alloc((size_t)CM*CE*2);      // [B,H,N,D]
  bf16* kk    = (bf16*)alloc((size_t)CM*CE*2);      // [B,H,N,D]
  bf16* vT    = (bf16*)alloc((size_t)CM*CE*2);      // [B,H,D,N]
  bf16* aO    = (bf16*)alloc((size_t)CM*CE*2);      // attn out [B,N,E]
  float* x2   = (float*)alloc((size_t)CM*CE*4);     // f32 trunk after proj
  bf16* hmlp  = q;  // reuse q..aO (4x8MB contiguous = 32MB) for bf16 [4096,4096]

  prep_k<<<3072+CM,256,0,stream>>>(w_qkv, wqkvT, x, g1, be1, h1);

  qkvt_k<<<768+9216,256,0,stream>>>(h1, wqkvT, b_qkv, q, kk, vT,
                                    w_proj, wprojT, w_fc1, wfc1T,
                                    w_fc2, wfc2T);
  attn_k<<<dim3(CN/128, CB*CH),256,0,stream>>>(q, kk, vT, aO);
  gemm_k<EP_RES,64><<<dim3(1024/64, CM/128),256,0,stream>>>(
      aO, wprojT, b_proj, x, x2, nullptr, 1024, 1024);
  ln_k<<<CM,256,0,stream>>>(x2, g2, be2, h1);
  gemm_k<EP_GELU,128><<<dim3(4096/128, CM/128),256,0,stream>>>(
      h1, wfc1T, b_fc1, nullptr, nullptr, hmlp, 1024, 4096);
  gemm_k<EP_RES,64><<<dim3(1024/64, CM/128),256,0,stream>>>(
      hmlp, wfc2T, b_fc2, x2, out, nullptr, 4096, 1024);
}

// Round 12
// 333.303 us; speedup vs baseline: 1.0250x; 1.0250x over previous
//
#include <hip/hip_runtime.h>
#include <hip/hip_bf16.h>
#include <cmath>

// ---------------------------------------------------------------------------
// TransformerEncoderLayer, fp32 in/out (bf16 MFMA internally), MI355X gfx950.
// Pipeline: prep(4x weight-transpose + LN1, ONE launch)
//           -> GEMM(qkv,scatter, Q prescaled) -> flash-attn(pipelined)
//           -> GEMM(proj,+x -> f32 x2) -> LN2 -> GEMM(fc1,GELU)
//           -> GEMM(fc2,+x2 -> f32 out)
// v14 = R10 verbatim (best measured: 334.3us). R11's transpose/GEMM
// co-scheduling REGRESSED (+7.3us): transpose blocks displace GEMM blocks
// from CU slots and pollute L2 on the critical path. Serial specialized
// schedule wins. Evidence ledger (R1-R11), all families CLOSED:
//   - GEMM BN=128 (qkv/fc1): 2-buffer __syncthreads loop, ~590 TF plateau;
//     bigger tiles / 8-phase raw-barrier / 3-deep counted-vmcnt / 64x64-wave
//     all REGRESSED (R2/R3/R4/R8). fc2 geometry can't feed the 256² escape.
//   - GEMM BN=64 (proj/fc2): NBUF=3 + vmcnt(6) counted prefetch (R6, +2us).
//   - attn: KVBLK=64 double-buffered stage-before-compute, 3 blk/CU (R10);
//     Q prescaled 0.125*log2e -> bare exp2 (R7); row-sum via ones-MFMA (R7);
//     XCD remap (R1, FETCH 70->12MB); guarded exp2 builtin (R5, +9us vs OCML).
//   - launches: prep fuses 4 transposes + LN1 (R5/R10); further fusion into
//     GEMM launches REGRESSED (R11).
// ---------------------------------------------------------------------------

typedef __hip_bfloat16 bf16;
typedef __bf16 bf16x8 __attribute__((ext_vector_type(8)));
typedef __bf16 bf16x4v __attribute__((ext_vector_type(4)));
typedef float  f32x4  __attribute__((ext_vector_type(4)));

#define CB 2
#define CN 2048
#define CE 1024
#define CH 16
#define CD 64
#define CMLP 4096
#define CM (CB*CN)   // 4096 tokens

#define PS2 72       // attn P-tile LDS row stride (elems), 64 keys + pad

#define QPRE 0.18033688011112042f   // 0.125 * log2(e), folded into Q
#if __has_builtin(__builtin_amdgcn_exp2f)
#define EXP2(s) __builtin_amdgcn_exp2f(s)
#else
#define EXP2(s) __expf((s)*0.69314718055994531f)
#endif

__device__ __forceinline__ float b2f(bf16 v){ return __bfloat162float(v); }
__device__ __forceinline__ bf16  f2b(float v){ return __float2bfloat16(v); }

__device__ __forceinline__ void gl_lds16(const void* g, void* l){
  __builtin_amdgcn_global_load_lds((__attribute__((address_space(1))) void*)g,
                                   (__attribute__((address_space(3))) void*)l,
                                   16, 0, 0);
}

#define FENCE asm volatile("" ::: "memory")
#define BAR   do{ FENCE; __builtin_amdgcn_s_barrier(); FENCE; }while(0)
#define VMW6  asm volatile("s_waitcnt vmcnt(6)" ::: "memory")
#define VMW0  asm volatile("s_waitcnt vmcnt(0)" ::: "memory")

// prep: 4 weight transposes (f32 [K,N] -> bf16 [N,K]) + LN1, one launch.
// blocks 0..12287: transpose tiles (qkv 3072, proj 1024, fc1 4096, fc2 4096)
// blocks 12288..16383: LN1 rows.
__global__ __launch_bounds__(256) void prep_k(
  const float* __restrict__ i0, bf16* __restrict__ o0,
  const float* __restrict__ i1, bf16* __restrict__ o1,
  const float* __restrict__ i2, bf16* __restrict__ o2,
  const float* __restrict__ i3, bf16* __restrict__ o3,
  const float* __restrict__ x,  const float* __restrict__ g,
  const float* __restrict__ be, bf16* __restrict__ lnout)
{
  __shared__ float tile[32][33];
  __shared__ float red[8];
  __shared__ float mu_s, rs_s;
  int t = blockIdx.x;
  const int tid = threadIdx.x;
  if(t >= 12288){
    // ---- LayerNorm row ----
    const int row = t - 12288;
    const float4 v4 = ((const float4*)(x + (size_t)row*CE))[tid];
    float v[4] = {v4.x, v4.y, v4.z, v4.w};
    float s=0.f, s2=0.f;
    #pragma unroll
    for(int i=0;i<4;i++){ s+=v[i]; s2+=v[i]*v[i]; }
    #pragma unroll
    for(int off=32; off>0; off>>=1){ s += __shfl_down(s,off); s2 += __shfl_down(s2,off); }
    const int wv=tid>>6, ln=tid&63;
    if(ln==0){ red[wv]=s; red[4+wv]=s2; }
    __syncthreads();
    if(tid==0){
      float S=red[0]+red[1]+red[2]+red[3], S2=red[4]+red[5]+red[6]+red[7];
      float mu=S/CE;
      mu_s=mu; rs_s=rsqrtf(S2/CE - mu*mu + 1e-5f);
    }
    __syncthreads();
    const float mu=mu_s, rs=rs_s;
    #pragma unroll
    for(int i=0;i<4;i++){
      int c=tid*4+i;
      lnout[(size_t)row*CE+c] = f2b((v[i]-mu)*rs*g[c] + be[c]);
    }
    return;
  }
  // ---- transpose tile ----
  const float* in; bf16* out; int K, N, nx;
  if(t < 3072){            in=i0; out=o0; K=1024; N=3072; nx=96; }
  else if(t < 4096){ t-=3072; in=i1; out=o1; K=1024; N=1024; nx=32; }
  else if(t < 8192){ t-=4096; in=i2; out=o2; K=1024; N=4096; nx=128; }
  else {             t-=8192; in=i3; out=o3; K=4096; N=1024; nx=32; }
  const int n0 = (t%nx)*32, k0 = (t/nx)*32;
  const int tx = tid & 31;
  const int ty = tid >> 5;   // 0..7
  #pragma unroll
  for(int i=0;i<32;i+=8) tile[ty+i][tx] = in[(size_t)(k0+ty+i)*N + n0+tx];
  __syncthreads();
  #pragma unroll
  for(int i=0;i<32;i+=8) out[(size_t)(n0+ty+i)*K + k0+tx] = f2b(tile[tx][ty+i]);
}

// LayerNorm: one row (E=1024) per 256-thread block; f32 in -> bf16 out
__global__ __launch_bounds__(256) void ln_k(const float* __restrict__ x,
                                            const float* __restrict__ g,
                                            const float* __restrict__ be,
                                            bf16* __restrict__ out){
  const int row = blockIdx.x;
  const int t = threadIdx.x;
  const float4 v4 = ((const float4*)(x + (size_t)row*CE))[t];
  float v[4] = {v4.x, v4.y, v4.z, v4.w};
  float s=0.f, s2=0.f;
  #pragma unroll
  for(int i=0;i<4;i++){ s+=v[i]; s2+=v[i]*v[i]; }
  #pragma unroll
  for(int off=32; off>0; off>>=1){ s += __shfl_down(s,off); s2 += __shfl_down(s2,off); }
  __shared__ float red[8];
  __shared__ float mu_s, rs_s;
  const int wv=t>>6, ln=t&63;
  if(ln==0){ red[wv]=s; red[4+wv]=s2; }
  __syncthreads();
  if(t==0){
    float S=red[0]+red[1]+red[2]+red[3], S2=red[4]+red[5]+red[6]+red[7];
    float mu=S/CE;
    mu_s=mu; rs_s=rsqrtf(S2/CE - mu*mu + 1e-5f);
  }
  __syncthreads();
  const float mu=mu_s, rs=rs_s;
  #pragma unroll
  for(int i=0;i<4;i++){
    int c=t*4+i;
    out[(size_t)row*CE+c] = f2b((v[i]-mu)*rs*g[c] + be[c]);
  }
}

#define EP_QKV 0
#define EP_RES 1
#define EP_GELU 2

// C = A[M,K](bf16) * BT[N,K](bf16)^T (+f32 bias; epilogue per MODE)
// Tile 128 x BN, BK=64; 4 waves, each 64 x BN/2 (MI=4, NJ=BN/32).
// Requires gridDim.y == 32 (M=4096) for the XCD remap.
template<int MODE, int BN>
__global__ __launch_bounds__(256,2) void gemm_k(
  const bf16* __restrict__ A, const bf16* __restrict__ BT,
  const float* __restrict__ bias, const float* __restrict__ res,
  float* __restrict__ Cf, bf16* __restrict__ Cb,
  bf16* __restrict__ Cq, bf16* __restrict__ Ck, bf16* __restrict__ Cv,
  int Ksz, int Nsz)
{
  constexpr int NJ = BN/32;           // B frags per wave (2 or 4)
  constexpr int NBUF = (BN==64) ? 3 : 2;
  __shared__ __align__(16) bf16 Alds[NBUF][128*64];
  __shared__ __align__(16) bf16 Blds[NBUF][BN*64];
  const int tid = threadIdx.x;
  const int wave = tid>>6, lane = tid&63;
  const int m16 = lane&15, quad = lane>>4;
  const int wi = wave>>1, wj = wave&1;

  // XCD co-location: same m-tile -> same lin%8 -> same XCD L2 holds A-tile.
  const int lin = blockIdx.x + gridDim.x*blockIdx.y;
  const int m_idx = (lin&7) + 8*((lin>>3)&3);
  const int n_idx = lin>>5;
  const size_t m0 = (size_t)m_idx*128;
  const size_t n0 = (size_t)n_idx*BN;

  f32x4 acc[4][NJ] = {};

  // staging: instr j covers 8 rows; lane -> row +lane/8, swizzled chunk
  const int srow8 = lane>>3;                   // 0..7
  const int schk  = ((lane&7)^srow8)*8;        // elem offset, XOR swizzle
  const bf16* pA = A  + (m0 + 32*wave      + srow8)*(size_t)Ksz + schk;
  const bf16* pB = BT + (n0 + (BN/4)*wave  + srow8)*(size_t)Ksz + schk;

  auto stage = [&](int buf, const bf16* gA, const bf16* gB){
    bf16* lA = &Alds[buf][wave*2048];          // 32 rows * 64 elems
    bf16* lB = &Blds[buf][wave*(BN*16)];       // BN/4 rows * 64 elems
    #pragma unroll
    for(int j=0;j<4;j++)  gl_lds16(gA + (size_t)(j*8)*Ksz, lA + j*512);
    #pragma unroll
    for(int j=0;j<NJ;j++) gl_lds16(gB + (size_t)(j*8)*Ksz, lB + j*512);
  };
  auto compute = [&](int buf){
    #pragma unroll
    for(int w=0;w<2;w++){
      const int sw = (m16&7);
      bf16x8 af[4], bfr[NJ];
      #pragma unroll
      for(int i=0;i<4;i++){
        const int row = wi*64+16*i+m16;
        af[i] = *(const bf16x8*)(&Alds[buf][row*64 + ((w*4+quad)^sw)*8]);
      }
      #pragma unroll
      for(int j=0;j<NJ;j++){
        const int row = wj*(BN/2)+16*j+m16;
        bfr[j] = *(const bf16x8*)(&Blds[buf][row*64 + ((w*4+quad)^sw)*8]);
      }
      #pragma unroll
      for(int i=0;i<4;i++)
        #pragma unroll
        for(int j=0;j<NJ;j++)
          acc[i][j] = __builtin_amdgcn_mfma_f32_16x16x32_bf16(af[i], bfr[j], acc[i][j], 0,0,0);
    }
  };

  const int kIters = Ksz/64;
  if constexpr (BN==64){
    // 3-buffer, 2-tile-ahead prefetch; counted vmcnt + raw barrier per iter.
    stage(0, pA, pB); pA += 64; pB += 64;
    stage(1, pA, pB); pA += 64; pB += 64;
    int bc = 0, bs = 2;
    for(int kb=0; kb<kIters; ++kb){
      if(kb==kIters-1){ VMW0; } else { VMW6; }   // own tile-kb loads landed
      BAR;                                        // -> all waves' tile kb
      if(kb+2<kIters){ stage(bs, pA, pB); pA += 64; pB += 64; }
      compute(bc);
      bc = (bc==2)?0:bc+1;
      bs = (bs==2)?0:bs+1;
    }
  } else {
    // Proven 2-buffer loop: ONE __syncthreads per iter (implicit vmcnt(0)
    // drain waits tile kb issued a full compute phase earlier).
    stage(0, pA, pB); pA += 64; pB += 64;
    for(int kb=0; kb<kIters; ++kb){
      __syncthreads();                  // tile kb landed; compute(kb-1) done
      if(kb+1<kIters){ stage((kb+1)&1, pA, pB); pA += 64; pB += 64; }
      compute(kb&1);                    // overlaps tile kb+1 load latency
    }
  }

  // epilogue: elem (row = m0+wi*64+16i+quad*4+r, col = n0+wj*(BN/2)+16j+m16)
  #pragma unroll
  for(int i=0;i<4;i++){
    #pragma unroll
    for(int j=0;j<NJ;j++){
      const int col = (int)n0 + wj*(BN/2) + 16*j + m16;
      const float bcol = bias[col];
      #pragma unroll
      for(int r=0;r<4;r++){
        const int row = (int)m0 + wi*64 + 16*i + quad*4 + r;
        float v = acc[i][j][r] + bcol;
        if constexpr (MODE==EP_QKV){
          const int b = row>>11, n = row&2047;
          const int which = col>>10, cc = col&1023;
          const int h = cc>>6, d = cc&63;
          if(which==0)      Cq[(((size_t)(b*CH+h))*CN+n)*CD + d] = f2b(v*QPRE);
          else if(which==1) Ck[(((size_t)(b*CH+h))*CN+n)*CD + d] = f2b(v);
          else              Cv[(((size_t)(b*CH+h))*CD+d)*CN + n] = f2b(v);
        } else if constexpr (MODE==EP_RES){
          v += res[(size_t)row*Nsz+col];
          Cf[(size_t)row*Nsz+col] = v;
        } else { // EP_GELU: tanh-form, branch-free.
          const float u2 = 1.5957691216f*(v + 0.044715f*v*v*v);
          v = v * (1.f/(1.f + __expf(-u2)));
          Cb[(size_t)row*Nsz+col] = f2b(v);
        }
      }
    }
  }
}

// Flash attention v5 (pipelined): grid (16,32), XCD remap (all 16 q-blocks
// of one (b,h) share lin%8). 4 waves; wave = 32 q-rows. KVBLK=64, K/V
// double-buffered: stage(t+1) issued BEFORE compute(t), ONE barrier/iter
// (R1-GEMM choreography). P-tile wave-private (no barrier). LDS ~50KB ->
// 3 blk/CU. Q pre-scaled -> bare exp2; row-sum via ones-MFMA.
// Q,K: bf16 [B,H,N,D]; Vt: bf16 [B,H,D,N]; O: bf16 [B,N,E] (col = h*64+d)
__global__ __launch_bounds__(256,2) void attn_k(
  const bf16* __restrict__ Q, const bf16* __restrict__ Kx,
  const bf16* __restrict__ Vt, bf16* __restrict__ O)
{
  const int lin = blockIdx.x + gridDim.x*blockIdx.y;
  const int bh = (lin&7) + 8*(lin>>7);
  const int qblk = (lin>>3)&15;
  const int b = bh>>4, h = bh&15;
  const int tid = threadIdx.x;
  const int wave = tid>>6, lane = tid&63;
  const int m16 = lane&15, quad = lane>>4;
  const int sw = m16&7;
  const int q0 = qblk*128 + wave*32;

  const bf16* Qb = Q  + (size_t)bh*CN*CD;
  const bf16* Kb = Kx + (size_t)bh*CN*CD;
  const bf16* Vb = Vt + (size_t)bh*CD*CN;

  bf16x8 qf[2][2];
  #pragma unroll
  for(int g=0;g<2;g++){
    const bf16* qp = Qb + (size_t)(q0+g*16+m16)*CD + quad*8;
    qf[g][0] = *(const bf16x8*)(qp);
    qf[g][1] = *(const bf16x8*)(qp + 32);
  }

  bf16x8 onesv;
  #pragma unroll
  for(int i=0;i<8;i++) onesv[i] = (__bf16)1.0f;

  f32x4 lacc[2] = {};
  f32x4 oacc[2][4] = {};

  __shared__ __align__(16) bf16 Klds[2][64*64];   // 8 KB per buf
  __shared__ __align__(16) bf16 Vlds[2][64*64];   // 8 KB per buf
  __shared__ __align__(16) bf16 Plds[4][32*PS2];  // 18 KB
  bf16* Pw = &Plds[wave][0];

  // staging: wave covers 16 K-rows and 16 V(d)-rows per tile (2 gl_lds each,
  // 8 rows x 8 slots); slot s of row r holds global chunk s^(r&7).
  const int srow8 = lane>>3;                    // 0..7 (row in 8-group)
  const int kchk  = (lane&7) ^ srow8;           // swizzled chunk
  const bf16* pK = Kb + (size_t)(wave*16 + srow8)*CD + kchk*8;
  const bf16* pV = Vb + (size_t)(wave*16 + srow8)*CN + kchk*8;
  const int ldso = wave*1024;                   // 16 rows * 64 elems

  auto stage = [&](int buf, int kt){
    #pragma unroll
    for(int j=0;j<2;j++){
      gl_lds16(pK + ((size_t)kt + (size_t)j*8)*CD, &Klds[buf][ldso + j*512]);
      gl_lds16(pV + (size_t)j*8*CN + kt,           &Vlds[buf][ldso + j*512]);
    }
  };

  stage(0, 0);
  const int nT = CN/64;   // 32 tiles
  for(int t=0; t<nT; ++t){
    __syncthreads();                 // tile t landed; compute(t-1) done
    if(t+1<nT) stage((t+1)&1, (t+1)*64);
    const bf16* Kl = &Klds[t&1][0];
    const bf16* Vl = &Vlds[t&1][0];

    // S^T = K * Q^T : 4 f-tiles of 16 key-rows
    f32x4 sf0[4], sf1[4];
    #pragma unroll
    for(int f=0;f<4;f++){
      const bf16* kb = Kl + (f*16+m16)*64;
      bf16x8 k0 = *(const bf16x8*)(kb + ((quad   ^ sw)*8));
      bf16x8 k1 = *(const bf16x8*)(kb + (((quad+4)^ sw)*8));
      f32x4 t0 = {}, t1 = {};
      t0 = __builtin_amdgcn_mfma_f32_16x16x32_bf16(k0, qf[0][0], t0, 0,0,0);
      t0 = __builtin_amdgcn_mfma_f32_16x16x32_bf16(k1, qf[0][1], t0, 0,0,0);
      t1 = __builtin_amdgcn_mfma_f32_16x16x32_bf16(k0, qf[1][0], t1, 0,0,0);
      t1 = __builtin_amdgcn_mfma_f32_16x16x32_bf16(k1, qf[1][1], t1, 0,0,0);
      sf0[f]=t0; sf1[f]=t1;
    }
    // P = exp2(S) -> bf16, packed b64 stores into wave-private P-tile
    #pragma unroll
    for(int f=0;f<4;f++){
      bf16x4v p0, p1;
      #pragma unroll
      for(int r=0;r<4;r++){
        p0[r] = (__bf16)EXP2(sf0[f][r]);
        p1[r] = (__bf16)EXP2(sf1[f][r]);
      }
      *(bf16x4v*)(Pw + (size_t)m16*PS2      + f*16 + quad*4) = p0;
      *(bf16x4v*)(Pw + (size_t)(16+m16)*PS2 + f*16 + quad*4) = p1;
    }
    asm volatile("s_waitcnt lgkmcnt(0)" ::: "memory");
    // O += P * V ; li += P * 1  (2 c-chunks of 32 keys)
    #pragma unroll
    for(int c=0;c<2;c++){
      const bf16x8 ap0 = *(const bf16x8*)(Pw + (size_t)m16*PS2      + c*32 + quad*8);
      const bf16x8 ap1 = *(const bf16x8*)(Pw + (size_t)(16+m16)*PS2 + c*32 + quad*8);
      lacc[0] = __builtin_amdgcn_mfma_f32_16x16x32_bf16(ap0, onesv, lacc[0], 0,0,0);
      lacc[1] = __builtin_amdgcn_mfma_f32_16x16x32_bf16(ap1, onesv, lacc[1], 0,0,0);
      #pragma unroll
      for(int dt=0;dt<4;dt++){
        const int d = dt*16+m16;
        bf16x8 bv = *(const bf16x8*)(Vl + d*64 + (((c*4+quad) ^ sw)*8));
        oacc[0][dt] = __builtin_amdgcn_mfma_f32_16x16x32_bf16(ap0, bv, oacc[0][dt], 0,0,0);
        oacc[1][dt] = __builtin_amdgcn_mfma_f32_16x16x32_bf16(ap1, bv, oacc[1][dt], 0,0,0);
      }
    }
  }
  // lacc[g][r] = row-sum for q-row g*16+quad*4+r (same value in all 16 cols)
  #pragma unroll
  for(int g=0;g<2;g++){
    float linv[4];
    #pragma unroll
    for(int r=0;r<4;r++) linv[r] = 1.f / lacc[g][r];
    #pragma unroll
    for(int dt=0;dt<4;dt++){
      #pragma unroll
      for(int r=0;r<4;r++){
        const int row = q0 + g*16 + quad*4 + r;
        O[((size_t)(b*CN+row))*CE + h*CD + dt*16 + m16] = f2b(oacc[g][dt][r]*linv[r]);
      }
    }
  }
}

extern "C" void kernel_launch(void* const* d_in, const int* in_sizes, int n_in,
                              void* d_out, int out_size, void* d_ws, size_t ws_size,
                              hipStream_t stream)
{
  (void)in_sizes; (void)n_in; (void)out_size; (void)ws_size;
  const float* x     = (const float*)d_in[0];
  const float* w_qkv = (const float*)d_in[1];
  const float* b_qkv = (const float*)d_in[2];
  const float* w_proj= (const float*)d_in[3];
  const float* b_proj= (const float*)d_in[4];
  const float* g1    = (const float*)d_in[5];
  const float* be1   = (const float*)d_in[6];
  const float* g2    = (const float*)d_in[7];
  const float* be2   = (const float*)d_in[8];
  const float* w_fc1 = (const float*)d_in[9];
  const float* b_fc1 = (const float*)d_in[10];
  const float* w_fc2 = (const float*)d_in[11];
  const float* b_fc2 = (const float*)d_in[12];
  float* out = (float*)d_out;

  char* ws = (char*)d_ws;
  size_t off = 0;
  auto alloc = [&](size_t bytes)->char*{
    char* p = ws + off;
    off += (bytes + 255) & ~(size_t)255;
    return p;
  };
  bf16* wqkvT = (bf16*)alloc((size_t)3072*1024*2);  // [3E, E]
  bf16* wprojT= (bf16*)alloc((size_t)1024*1024*2);  // [E, E]
  bf16* wfc1T = (bf16*)alloc((size_t)4096*1024*2);  // [MLP, E]
  bf16* wfc2T = (bf16*)alloc((size_t)1024*4096*2);  // [E, MLP]
  bf16* h1    = (bf16*)alloc((size_t)CM*CE*2);      // LN out (reused for LN2)
  bf16* q     = (bf16*)alloc((size_t)CM*CE*2);      // [B,H,N,D]
  bf16* kk    = (bf16*)alloc((size_t)CM*CE*2);      // [B,H,N,D]
  bf16* vT    = (bf16*)alloc((size_t)CM*CE*2);      // [B,H,D,N]
  bf16* aO    = (bf16*)alloc((size_t)CM*CE*2);      // attn out [B,N,E]
  float* x2   = (float*)alloc((size_t)CM*CE*4);     // f32 trunk after proj
  bf16* hmlp  = q;  // reuse q..aO (4x8MB contiguous = 32MB) for bf16 [4096,4096]

  prep_k<<<12288+CM,256,0,stream>>>(w_qkv, wqkvT, w_proj, wprojT,
                                    w_fc1, wfc1T, w_fc2, wfc2T,
                                    x, g1, be1, h1);

  gemm_k<EP_QKV,128><<<dim3(3072/128, CM/128),256,0,stream>>>(
      h1, wqkvT, b_qkv, nullptr, nullptr, nullptr, q, kk, vT, 1024, 3072);
  attn_k<<<dim3(CN/128, CB*CH),256,0,stream>>>(q, kk, vT, aO);
  gemm_k<EP_RES,64><<<dim3(1024/64, CM/128),256,0,stream>>>(
      aO, wprojT, b_proj, x, x2, nullptr, nullptr,nullptr,nullptr, 1024, 1024);
  ln_k<<<CM,256,0,stream>>>(x2, g2, be2, h1);
  gemm_k<EP_GELU,128><<<dim3(4096/128, CM/128),256,0,stream>>>(
      h1, wfc1T, b_fc1, nullptr, nullptr, hmlp, nullptr,nullptr,nullptr, 1024, 4096);
  gemm_k<EP_RES,64><<<dim3(1024/64, CM/128),256,0,stream>>>(
      hmlp, wfc2T, b_fc2, x2, out, nullptr, nullptr,nullptr,nullptr, 4096, 1024);
}